// Round 12
// baseline (349.527 us; speedup 1.0000x reference)
//
#include <hip/hip_runtime.h>
#include <hip/hip_fp16.h>

typedef unsigned int uint;
typedef unsigned short ushort;

typedef __attribute__((ext_vector_type(8))) _Float16 f16x8;
typedef __attribute__((ext_vector_type(4))) float f32x4;

#define TOK 256
#define OUTF 11008
#define INF 4096
#define BM 256
#define BN 64
#define NT2 172  // OUTF / BN
#define CVT_BLKS 2048
#define KSPLIT 4

__device__ __constant__ float NF4_TBL[16] = {
    -1.0f, -0.6961928009986877f, -0.5250730514526367f, -0.39491748809814453f,
    -0.28444138169288635f, -0.18477343022823334f, -0.09105003625154495f, 0.0f,
    0.07958029955625534f, 0.16093020141124725f, 0.24611230194568634f,
    0.33791524171829224f, 0.44070982933044434f, 0.5626170039176941f,
    0.7229568362236023f, 1.0f};

__device__ __forceinline__ ushort f2h(float f) {
  return __half_as_ushort(__float2half(f));
}

// async global->LDS, 16B per lane; lds base wave-uniform + lane*16
__device__ __forceinline__ void async_cp16(const void* g, void* l) {
  __builtin_amdgcn_global_load_lds(
      (const __attribute__((address_space(1))) uint*)g,
      (__attribute__((address_space(3))) uint*)l, 16, 0, 0);
}

// table value via VGPR crossbar (conflict-free); lanes 0..15 of each 16 hold the table
__device__ __forceinline__ float nf4v(int c, int tbits) {
  return __int_as_float(__builtin_amdgcn_ds_bpermute(c << 2, tbits));
}

// 4 raw codes -> 4 scaled halfs (8B)
__device__ __forceinline__ uint2 dq4(int4 c, __half2 ax2, int tbits) {
  __half2 h0 = __floats2half2_rn(nf4v(c.x, tbits), nf4v(c.y, tbits));
  __half2 h1 = __floats2half2_rn(nf4v(c.z, tbits), nf4v(c.w, tbits));
  h0 = __hmul2(h0, ax2);
  h1 = __hmul2(h1, ax2);
  union { __half2 h[2]; uint2 u; } r;
  r.h[0] = h0; r.h[1] = h1;
  return r.u;
}

// kernel 1 (fused): blocks [0,CVT_BLKS): x->f16, lB->padded f16, ZERO out;
// blocks [CVT_BLKS, CVT_BLKS+TOK): xa2 (overlaps the convert).
__global__ __launch_bounds__(256)
void prep_kernel(const float4* __restrict__ x4, ushort4* __restrict__ xh4,
                 const float4* __restrict__ lB4, ushort4* __restrict__ lBh4,
                 const float* __restrict__ x, const float* __restrict__ lA,
                 ushort* __restrict__ xa2, float4* __restrict__ out4) {
  if (blockIdx.x < CVT_BLKS) {
    const int stride = CVT_BLKS * blockDim.x;
    const int t0 = blockIdx.x * blockDim.x + threadIdx.x;
    for (int i = t0; i < TOK * INF / 4; i += stride) {
      float4 v = x4[i];
      ushort4 o;
      o.x = f2h(v.x); o.y = f2h(v.y); o.z = f2h(v.z); o.w = f2h(v.w);
      xh4[i] = o;
    }
    for (int i = t0; i < OUTF * 16; i += stride) {
      int n = i >> 4, jq = i & 15;
      ushort4 o = {0, 0, 0, 0};
      if (jq < 4) {
        float4 v = lB4[n * 4 + jq];
        o.x = f2h(v.x); o.y = f2h(v.y); o.z = f2h(v.z); o.w = f2h(v.w);
      }
      lBh4[i] = o;
    }
    const float4 z = {0.f, 0.f, 0.f, 0.f};
    for (int i = t0; i < TOK * OUTF / 4; i += stride) out4[i] = z;
  } else {
    // xa: one block per token m; xa2[m][j] = f16(2 * sum_k x[m][k]*lA[j][k])
    const int m = blockIdx.x - CVT_BLKS;
    const int t = threadIdx.x;
    const float4* xm4 = (const float4*)(x + (size_t)m * INF);
    const float4* lA4 = (const float4*)lA;
    float4 xv[4];
#pragma unroll
    for (int c = 0; c < 4; ++c) xv[c] = xm4[c * 256 + t];
    float acc[16];
#pragma unroll
    for (int j = 0; j < 16; ++j) {
      acc[j] = 0.f;
#pragma unroll
      for (int c = 0; c < 4; ++c) {
        float4 a = lA4[j * (INF / 4) + c * 256 + t];
        acc[j] += xv[c].x * a.x + xv[c].y * a.y + xv[c].z * a.z + xv[c].w * a.w;
      }
    }
#pragma unroll
    for (int j = 0; j < 16; ++j)
#pragma unroll
      for (int s = 32; s > 0; s >>= 1) acc[j] += __shfl_xor(acc[j], s, 64);
    __shared__ float red[4][16];
    const int w = t >> 6, l = t & 63;
    if (l == 0) {
#pragma unroll
      for (int j = 0; j < 16; ++j) red[w][j] = acc[j];
    }
    __syncthreads();
    if (t < 64) {
      ushort v = 0;
      if (t < 16) {
        float s = red[0][t] + red[1][t] + red[2][t] + red[3][t];
        v = f2h(2.0f * s);
      }
      xa2[m * 64 + t] = v;
    }
  }
}

// kernel 2: single-pass fused dequant GEMM (R9 skeleton, best measured).
// Deltas: q(s+1) issued right after barrier A(s) into parity regs (deep slack);
// epilogue = fp32 HW atomics onto pre-zeroed out (no partials, no reduce pass).
__global__ __launch_bounds__(256, 3)
void gemm_kernel(const int* __restrict__ qc, const float* __restrict__ am,
                 const ushort* __restrict__ xh, const ushort* __restrict__ lBh,
                 const ushort* __restrict__ xa2, float* __restrict__ out, int nst) {
  __shared__ ushort Abuf[BM * 64];  // 32 KB, octet-swizzled (proven R3..R9)
  __shared__ ushort Bbuf[64 * 64];  // 8 KB, octet-swizzled
  __shared__ float Qax[1024];       // 4 KB: 16 k-blocks of amax, [j4][64 rows][4]

  const int tid = threadIdx.x;
  const int w = tid >> 6;
  const int l = tid & 63;
  const int chunk = l >> 4;  // 0..3
  const int rlo = l & 15;
  const int split = blockIdx.x / NT2;
  const int ntile = blockIdx.x - split * NT2;
  const int n0 = ntile * BN;
  const int kb0 = split * nst;  // in 64-k blocks

  const int tbits = __float_as_int(NF4_TBL[l & 15]);

  // A staging geometry (verified R3..R9)
  const int arow = w * 8 + (l >> 3);
  const int acol = ((l & 7) ^ (l >> 3)) << 3;
  int aoff[2][4];
#pragma unroll
  for (int ks2 = 0; ks2 < 2; ++ks2) {
    const int cc = ks2 * 4 + chunk;
#pragma unroll
    for (int mt = 0; mt < 4; ++mt)
      aoff[ks2][mt] = (w * 64 + mt * 16 + rlo) * 64 + ((cc ^ (l & 7)) << 3);
  }

  // q-load geometry (coalesced, proven R9): pass p -> row p*16+(tid>>4), chunk tid&15
  const int qrg = tid >> 4;  // 0..15
  const int qch = tid & 15;  // 0..15
  const int* qbase[4];
  int bdst[4];
#pragma unroll
  for (int p = 0; p < 4; ++p) {
    int r = p * 16 + qrg;
    qbase[p] = qc + (size_t)(n0 + r) * INF + kb0 * 64 + qch * 4;
    bdst[p] = r * 64 + (((qch >> 1) ^ (r & 7)) << 3) + (qch & 1) * 4;
  }

  // b-frag LDS read offsets (swizzle-matched, proven R8/R9)
  int boff[2][4];
#pragma unroll
  for (int ks2 = 0; ks2 < 2; ++ks2)
#pragma unroll
    for (int nt = 0; nt < 4; ++nt)
      boff[ks2][nt] = (nt * 16 + rlo) * 64 + (((ks2 * 4 + chunk) ^ (rlo & 7)) << 3);

  f32x4 acc[4][4];
#pragma unroll
  for (int mt = 0; mt < 4; ++mt)
#pragma unroll
    for (int nt = 0; nt < 4; ++nt) acc[mt][nt] = (f32x4){0.f, 0.f, 0.f, 0.f};

  // prologue: A(0) DMA, Qax group 0 DMA, q(0) register loads into parity 0
  if (w == 0) {
#pragma unroll
    for (int j = 0; j < 4; ++j)
      async_cp16(am + (size_t)(n0 + l) * 64 + kb0 + j * 4, (char*)Qax + j * 1024);
  }
#pragma unroll
  for (int i = 0; i < 8; ++i) {
    const ushort* g = xh + (size_t)(i * 32 + arow) * INF + kb0 * 64 + acol;
    async_cp16(g, &Abuf[(i * 256 + w * 64) * 8]);
  }
  int4 qreg[2][4];
#pragma unroll
  for (int p = 0; p < 4; ++p) qreg[0][p] = *(const int4*)(qbase[p]);

  for (int s = 0; s < nst; ++s) {
    const int par = s & 1;
    __syncthreads();  // barrier A: drains A(s) DMA + q(s) loads

    // issue q(s+1) NOW into the other parity — deep slack (dequant+barrier+MFMA)
    if (s + 1 < nst) {
#pragma unroll
      for (int p = 0; p < 4; ++p)
        qreg[par ^ 1][p] = *(const int4*)(qbase[p] + (s + 1) * 64);
    }

    // dequant q(s) -> Bbuf (bpermute, conflict-free); amax per row from Qax
    const int sl = s & 15;
#pragma unroll
    for (int p = 0; p < 4; ++p) {
      int r = p * 16 + qrg;
      __half2 ax2 = __float2half2_rn(Qax[(sl >> 2) * 256 + r * 4 + (sl & 3)]);
      *(uint2*)&Bbuf[bdst[p]] = dq4(qreg[par][p], ax2, tbits);
    }
    // A frags to registers
    f16x8 areg[2][4];
#pragma unroll
    for (int ks2 = 0; ks2 < 2; ++ks2)
#pragma unroll
      for (int mt = 0; mt < 4; ++mt) areg[ks2][mt] = *(const f16x8*)&Abuf[aoff[ks2][mt]];

    __syncthreads();  // barrier B: Bbuf ready, Abuf consumed

    // issue A(s+1) DMA (drains at barrier A(s+1), after compute below)
    if (s + 1 < nst) {
      const int kb = kb0 + s + 1;
#pragma unroll
      for (int i = 0; i < 8; ++i) {
        const ushort* g = xh + (size_t)(i * 32 + arow) * INF + kb * 64 + acol;
        async_cp16(g, &Abuf[(i * 256 + w * 64) * 8]);
      }
    }

    // compute: 32 MFMAs from registers + Bbuf
#pragma unroll
    for (int ks2 = 0; ks2 < 2; ++ks2) {
      f16x8 b[4];
#pragma unroll
      for (int nt = 0; nt < 4; ++nt) b[nt] = *(const f16x8*)&Bbuf[boff[ks2][nt]];
#pragma unroll
      for (int mt = 0; mt < 4; ++mt)
#pragma unroll
        for (int nt = 0; nt < 4; ++nt)
          acc[mt][nt] = __builtin_amdgcn_mfma_f32_16x16x32_f16(areg[ks2][mt], b[nt], acc[mt][nt], 0, 0, 0);
    }
  }

  if (split == 0) {
    // lora K-extension: k in [0,32) (rank 16 + zero pad); direct register frags
    f16x8 a_l[4], b_l[4];
#pragma unroll
    for (int mt = 0; mt < 4; ++mt)
      a_l[mt] = *(const f16x8*)(xa2 + (size_t)(w * 64 + mt * 16 + rlo) * 64 + chunk * 8);
#pragma unroll
    for (int nt = 0; nt < 4; ++nt)
      b_l[nt] = *(const f16x8*)(lBh + (size_t)(n0 + nt * 16 + rlo) * 64 + chunk * 8);
#pragma unroll
    for (int mt = 0; mt < 4; ++mt)
#pragma unroll
      for (int nt = 0; nt < 4; ++nt)
        acc[mt][nt] = __builtin_amdgcn_mfma_f32_16x16x32_f16(a_l[mt], b_l[nt], acc[mt][nt], 0, 0, 0);
  }

  // epilogue: C/D layout col=lane&15, row=(lane>>4)*4+reg.
  // HW fp32 atomic add onto pre-zeroed out (4-way contention max).
#pragma unroll
  for (int mt = 0; mt < 4; ++mt) {
#pragma unroll
    for (int nt = 0; nt < 4; ++nt) {
      int c = n0 + nt * 16 + rlo;
#pragma unroll
      for (int r = 0; r < 4; ++r) {
        int row = w * 64 + mt * 16 + chunk * 4 + r;
        unsafeAtomicAdd(&out[(size_t)row * OUTF + c], acc[mt][nt][r]);
      }
    }
  }
}

extern "C" void kernel_launch(void* const* d_in, const int* in_sizes, int n_in,
                              void* d_out, int out_size, void* d_ws, size_t ws_size,
                              hipStream_t stream) {
  const float* x = (const float*)d_in[0];
  const int* qc = (const int*)d_in[1];
  const float* am = (const float*)d_in[2];
  const float* lA = (const float*)d_in[3];
  const float* lB = (const float*)d_in[4];
  float* out = (float*)d_out;

  const size_t off_lB = (size_t)TOK * INF * 2;            // 2.10 MB
  const size_t off_xa2 = off_lB + (size_t)OUTF * 64 * 2;  // +1.41 MB
  ushort* xh = (ushort*)d_ws;
  ushort* lBh = (ushort*)((char*)d_ws + off_lB);
  ushort* xa2 = (ushort*)((char*)d_ws + off_xa2);

  prep_kernel<<<CVT_BLKS + TOK, 256, 0, stream>>>(
      (const float4*)x, (ushort4*)xh, (const float4*)lB, (ushort4*)lBh,
      x, lA, xa2, (float4*)out);
  gemm_kernel<<<NT2 * KSPLIT, 256, 0, stream>>>(qc, am, xh, lBh, xa2, out, 64 / KSPLIT);
}

// Round 13
// 346.374 us; speedup vs baseline: 1.0091x; 1.0091x over previous
//
#include <hip/hip_runtime.h>
#include <hip/hip_fp16.h>

typedef unsigned int uint;
typedef unsigned short ushort;

typedef __attribute__((ext_vector_type(8))) _Float16 f16x8;
typedef __attribute__((ext_vector_type(4))) float f32x4;

#define TOK 256
#define OUTF 11008
#define INF 4096
#define BM 256
#define BN 64
#define NT2 172  // OUTF / BN
#define CVT_BLKS 2048
#define KSPLIT 4

__device__ __constant__ float NF4_TBL[16] = {
    -1.0f, -0.6961928009986877f, -0.5250730514526367f, -0.39491748809814453f,
    -0.28444138169288635f, -0.18477343022823334f, -0.09105003625154495f, 0.0f,
    0.07958029955625534f, 0.16093020141124725f, 0.24611230194568634f,
    0.33791524171829224f, 0.44070982933044434f, 0.5626170039176941f,
    0.7229568362236023f, 1.0f};

__device__ __forceinline__ ushort f2h(float f) {
  return __half_as_ushort(__float2half(f));
}

// async global->LDS, 16B per lane; lds base wave-uniform + lane*16
__device__ __forceinline__ void async_cp16(const void* g, void* l) {
  __builtin_amdgcn_global_load_lds(
      (const __attribute__((address_space(1))) uint*)g,
      (__attribute__((address_space(3))) uint*)l, 16, 0, 0);
}

// table value via VGPR crossbar (conflict-free); lanes 0..15 of each 16 hold the table
__device__ __forceinline__ float nf4v(int c, int tbits) {
  return __int_as_float(__builtin_amdgcn_ds_bpermute(c << 2, tbits));
}

// 4 raw codes -> 4 scaled halfs (8B)
__device__ __forceinline__ uint2 dq4(int4 c, __half2 ax2, int tbits) {
  __half2 h0 = __floats2half2_rn(nf4v(c.x, tbits), nf4v(c.y, tbits));
  __half2 h1 = __floats2half2_rn(nf4v(c.z, tbits), nf4v(c.w, tbits));
  h0 = __hmul2(h0, ax2);
  h1 = __hmul2(h1, ax2);
  union { __half2 h[2]; uint2 u; } r;
  r.h[0] = h0; r.h[1] = h1;
  return r.u;
}

// kernel 1 (fused): blocks [0,CVT_BLKS): x->f16, lB->padded f16;
// blocks [CVT_BLKS, CVT_BLKS+TOK): xa2 (overlaps the convert).
__global__ __launch_bounds__(256)
void prep_kernel(const float4* __restrict__ x4, ushort4* __restrict__ xh4,
                 const float4* __restrict__ lB4, ushort4* __restrict__ lBh4,
                 const float* __restrict__ x, const float* __restrict__ lA,
                 ushort* __restrict__ xa2) {
  if (blockIdx.x < CVT_BLKS) {
    const int stride = CVT_BLKS * blockDim.x;
    const int t0 = blockIdx.x * blockDim.x + threadIdx.x;
    for (int i = t0; i < TOK * INF / 4; i += stride) {
      float4 v = x4[i];
      ushort4 o;
      o.x = f2h(v.x); o.y = f2h(v.y); o.z = f2h(v.z); o.w = f2h(v.w);
      xh4[i] = o;
    }
    for (int i = t0; i < OUTF * 16; i += stride) {
      int n = i >> 4, jq = i & 15;
      ushort4 o = {0, 0, 0, 0};
      if (jq < 4) {
        float4 v = lB4[n * 4 + jq];
        o.x = f2h(v.x); o.y = f2h(v.y); o.z = f2h(v.z); o.w = f2h(v.w);
      }
      lBh4[i] = o;
    }
  } else {
    // xa: one block per token m; xa2[m][j] = f16(2 * sum_k x[m][k]*lA[j][k])
    const int m = blockIdx.x - CVT_BLKS;
    const int t = threadIdx.x;
    const float4* xm4 = (const float4*)(x + (size_t)m * INF);
    const float4* lA4 = (const float4*)lA;
    float4 xv[4];
#pragma unroll
    for (int c = 0; c < 4; ++c) xv[c] = xm4[c * 256 + t];
    float acc[16];
#pragma unroll
    for (int j = 0; j < 16; ++j) {
      acc[j] = 0.f;
#pragma unroll
      for (int c = 0; c < 4; ++c) {
        float4 a = lA4[j * (INF / 4) + c * 256 + t];
        acc[j] += xv[c].x * a.x + xv[c].y * a.y + xv[c].z * a.z + xv[c].w * a.w;
      }
    }
#pragma unroll
    for (int j = 0; j < 16; ++j)
#pragma unroll
      for (int s = 32; s > 0; s >>= 1) acc[j] += __shfl_xor(acc[j], s, 64);
    __shared__ float red[4][16];
    const int w = t >> 6, l = t & 63;
    if (l == 0) {
#pragma unroll
      for (int j = 0; j < 16; ++j) red[w][j] = acc[j];
    }
    __syncthreads();
    if (t < 64) {
      ushort v = 0;
      if (t < 16) {
        float s = red[0][t] + red[1][t] + red[2][t] + red[3][t];
        v = f2h(2.0f * s);
      }
      xa2[m * 64 + t] = v;
    }
  }
}

// kernel 2: single-pass fused dequant GEMM (R9 skeleton) + deep-slack q prefetch
// (q(s+1) issued right after barrier A into parity regs). Partial-slice epilogue.
__global__ __launch_bounds__(256, 3)
void gemm_kernel(const int* __restrict__ qc, const float* __restrict__ am,
                 const ushort* __restrict__ xh, const ushort* __restrict__ lBh,
                 const ushort* __restrict__ xa2, float* __restrict__ dest, int nst) {
  __shared__ ushort Abuf[BM * 64];  // 32 KB, octet-swizzled (proven R3..R9)
  __shared__ ushort Bbuf[64 * 64];  // 8 KB, octet-swizzled
  __shared__ float Qax[1024];       // 4 KB: 16 k-blocks of amax, [j4][64 rows][4]

  const int tid = threadIdx.x;
  const int w = tid >> 6;
  const int l = tid & 63;
  const int chunk = l >> 4;  // 0..3
  const int rlo = l & 15;
  const int split = blockIdx.x / NT2;
  const int ntile = blockIdx.x - split * NT2;
  const int n0 = ntile * BN;
  const int kb0 = split * nst;  // in 64-k blocks

  const int tbits = __float_as_int(NF4_TBL[l & 15]);

  // A staging geometry (verified R3..R9)
  const int arow = w * 8 + (l >> 3);
  const int acol = ((l & 7) ^ (l >> 3)) << 3;
  int aoff[2][4];
#pragma unroll
  for (int ks2 = 0; ks2 < 2; ++ks2) {
    const int cc = ks2 * 4 + chunk;
#pragma unroll
    for (int mt = 0; mt < 4; ++mt)
      aoff[ks2][mt] = (w * 64 + mt * 16 + rlo) * 64 + ((cc ^ (l & 7)) << 3);
  }

  // q-load geometry (coalesced, proven R9): pass p -> row p*16+(tid>>4), chunk tid&15
  const int qrg = tid >> 4;  // 0..15
  const int qch = tid & 15;  // 0..15
  const int* qbase[4];
  int bdst[4];
#pragma unroll
  for (int p = 0; p < 4; ++p) {
    int r = p * 16 + qrg;
    qbase[p] = qc + (size_t)(n0 + r) * INF + kb0 * 64 + qch * 4;
    bdst[p] = r * 64 + (((qch >> 1) ^ (r & 7)) << 3) + (qch & 1) * 4;
  }

  // b-frag LDS read offsets (swizzle-matched, proven R8/R9)
  int boff[2][4];
#pragma unroll
  for (int ks2 = 0; ks2 < 2; ++ks2)
#pragma unroll
    for (int nt = 0; nt < 4; ++nt)
      boff[ks2][nt] = (nt * 16 + rlo) * 64 + (((ks2 * 4 + chunk) ^ (rlo & 7)) << 3);

  f32x4 acc[4][4];
#pragma unroll
  for (int mt = 0; mt < 4; ++mt)
#pragma unroll
    for (int nt = 0; nt < 4; ++nt) acc[mt][nt] = (f32x4){0.f, 0.f, 0.f, 0.f};

  // prologue: A(0) DMA, Qax group 0 DMA, q(0) register loads into parity 0
  if (w == 0) {
#pragma unroll
    for (int j = 0; j < 4; ++j)
      async_cp16(am + (size_t)(n0 + l) * 64 + kb0 + j * 4, (char*)Qax + j * 1024);
  }
#pragma unroll
  for (int i = 0; i < 8; ++i) {
    const ushort* g = xh + (size_t)(i * 32 + arow) * INF + kb0 * 64 + acol;
    async_cp16(g, &Abuf[(i * 256 + w * 64) * 8]);
  }
  int4 qreg[2][4];
#pragma unroll
  for (int p = 0; p < 4; ++p) qreg[0][p] = *(const int4*)(qbase[p]);

  for (int s = 0; s < nst; ++s) {
    const int par = s & 1;
    __syncthreads();  // barrier A: drains A(s) DMA + q(s) loads

    // deep-slack q prefetch: issue q(s+1) NOW into the other parity
    if (s + 1 < nst) {
#pragma unroll
      for (int p = 0; p < 4; ++p)
        qreg[par ^ 1][p] = *(const int4*)(qbase[p] + (s + 1) * 64);
    }

    // dequant q(s) -> Bbuf (bpermute, conflict-free); amax per row from Qax
    const int sl = s & 15;
#pragma unroll
    for (int p = 0; p < 4; ++p) {
      int r = p * 16 + qrg;
      __half2 ax2 = __float2half2_rn(Qax[(sl >> 2) * 256 + r * 4 + (sl & 3)]);
      *(uint2*)&Bbuf[bdst[p]] = dq4(qreg[par][p], ax2, tbits);
    }
    // A frags to registers
    f16x8 areg[2][4];
#pragma unroll
    for (int ks2 = 0; ks2 < 2; ++ks2)
#pragma unroll
      for (int mt = 0; mt < 4; ++mt) areg[ks2][mt] = *(const f16x8*)&Abuf[aoff[ks2][mt]];

    __syncthreads();  // barrier B: Bbuf ready, Abuf consumed

    // issue A(s+1) DMA (drains at barrier A(s+1), after compute below)
    if (s + 1 < nst) {
      const int kb = kb0 + s + 1;
#pragma unroll
      for (int i = 0; i < 8; ++i) {
        const ushort* g = xh + (size_t)(i * 32 + arow) * INF + kb * 64 + acol;
        async_cp16(g, &Abuf[(i * 256 + w * 64) * 8]);
      }
    }

    // compute: 32 MFMAs from registers + Bbuf
#pragma unroll
    for (int ks2 = 0; ks2 < 2; ++ks2) {
      f16x8 b[4];
#pragma unroll
      for (int nt = 0; nt < 4; ++nt) b[nt] = *(const f16x8*)&Bbuf[boff[ks2][nt]];
#pragma unroll
      for (int mt = 0; mt < 4; ++mt)
#pragma unroll
        for (int nt = 0; nt < 4; ++nt)
          acc[mt][nt] = __builtin_amdgcn_mfma_f32_16x16x32_f16(areg[ks2][mt], b[nt], acc[mt][nt], 0, 0, 0);
    }
  }

  if (split == 0) {
    // lora K-extension: k in [0,32) (rank 16 + zero pad); direct register frags
    f16x8 a_l[4], b_l[4];
#pragma unroll
    for (int mt = 0; mt < 4; ++mt)
      a_l[mt] = *(const f16x8*)(xa2 + (size_t)(w * 64 + mt * 16 + rlo) * 64 + chunk * 8);
#pragma unroll
    for (int nt = 0; nt < 4; ++nt)
      b_l[nt] = *(const f16x8*)(lBh + (size_t)(n0 + nt * 16 + rlo) * 64 + chunk * 8);
#pragma unroll
    for (int mt = 0; mt < 4; ++mt)
#pragma unroll
      for (int nt = 0; nt < 4; ++nt)
        acc[mt][nt] = __builtin_amdgcn_mfma_f32_16x16x32_f16(a_l[mt], b_l[nt], acc[mt][nt], 0, 0, 0);
  }

  // epilogue: C/D layout col=lane&15, row=(lane>>4)*4+reg; each split owns a slice
  float* dst = dest + (size_t)split * TOK * OUTF;
#pragma unroll
  for (int mt = 0; mt < 4; ++mt) {
#pragma unroll
    for (int nt = 0; nt < 4; ++nt) {
      int c = n0 + nt * 16 + rlo;
#pragma unroll
      for (int r = 0; r < 4; ++r) {
        int row = w * 64 + mt * 16 + chunk * 4 + r;
        dst[(size_t)row * OUTF + c] = acc[mt][nt][r];
      }
    }
  }
}

// kernel 3: sum K-split partials -> out
__global__ void reduce_kernel(const float4* __restrict__ part, float4* __restrict__ out) {
  const int QN = TOK * OUTF / 4;
  int i = blockIdx.x * blockDim.x + threadIdx.x;
  if (i < QN) {
    float4 s = part[i];
#pragma unroll
    for (int s2 = 1; s2 < KSPLIT; ++s2) {
      float4 p = part[(size_t)s2 * QN + i];
      s.x += p.x; s.y += p.y; s.z += p.z; s.w += p.w;
    }
    out[i] = s;
  }
}

extern "C" void kernel_launch(void* const* d_in, const int* in_sizes, int n_in,
                              void* d_out, int out_size, void* d_ws, size_t ws_size,
                              hipStream_t stream) {
  const float* x = (const float*)d_in[0];
  const int* qc = (const int*)d_in[1];
  const float* am = (const float*)d_in[2];
  const float* lA = (const float*)d_in[3];
  const float* lB = (const float*)d_in[4];
  float* out = (float*)d_out;

  const size_t off_lB = (size_t)TOK * INF * 2;             // 2.10 MB
  const size_t off_xa2 = off_lB + (size_t)OUTF * 64 * 2;   // +1.41 MB
  const size_t off_part = off_xa2 + (size_t)TOK * 64 * 2;  // +32 KB = 3,538,944

  ushort* xh = (ushort*)d_ws;
  ushort* lBh = (ushort*)((char*)d_ws + off_lB);
  ushort* xa2 = (ushort*)((char*)d_ws + off_xa2);
  float* part = (float*)((char*)d_ws + off_part);  // 4 x 11.27 MB (ws ~688 MB)

  prep_kernel<<<CVT_BLKS + TOK, 256, 0, stream>>>(
      (const float4*)x, (ushort4*)xh, (const float4*)lB, (ushort4*)lBh, x, lA, xa2);
  gemm_kernel<<<NT2 * KSPLIT, 256, 0, stream>>>(qc, am, xh, lBh, xa2, part, 64 / KSPLIT);
  reduce_kernel<<<(TOK * OUTF / 4 + 255) / 256, 256, 0, stream>>>((const float4*)part,
                                                                  (float4*)out);
}